// Round 1
// 1324.747 us; speedup vs baseline: 1.0862x; 1.0862x over previous
//
#include <hip/hip_runtime.h>
#include <math.h>

// Problem constants
constexpr int B       = 1024;
constexpr int IN_DIM  = 768;
constexpr int HID     = 1024;
constexpr int CLIP    = 512;
constexpr int NG      = 4;
constexpr int DS      = 64;
constexpr int HD      = 64;
constexpr int DIN     = 2 * HID;            // 2048
constexpr int NH      = DIN / HD;           // 32
constexpr int CONV_DIM = DIN + 2 * NG * DS; // 2560
constexpr int DINP    = 2 * DIN + 2 * NG * DS + NH; // 4640
constexpr float EPS   = 1e-5f;

typedef __attribute__((ext_vector_type(8))) short bf16x8;   // 8 bf16 = 4 VGPR (MFMA A/B frag)
typedef __attribute__((ext_vector_type(4))) float f32x4;    // MFMA C/D frag
typedef __attribute__((ext_vector_type(8))) unsigned short u16x8;

__device__ __forceinline__ float sigmoidf_(float v) { return 1.f / (1.f + expf(-v)); }

// fp32 -> bf16 RNE
__device__ __forceinline__ unsigned short f2bf(float f) {
    unsigned int u = __float_as_uint(f);
    u += 0x7fffu + ((u >> 16) & 1u);
    return (unsigned short)(u >> 16);
}
__device__ __forceinline__ float bf2f(unsigned short h) {
    return __uint_as_float(((unsigned int)h) << 16);
}

// async global->LDS, 16B per lane. LDS dest is wave-uniform base + lane*16.
__device__ __forceinline__ void gload_lds16(const unsigned short* g, short* l) {
    __builtin_amdgcn_global_load_lds(
        (const __attribute__((address_space(1))) unsigned int*)(const void*)g,
        (__attribute__((address_space(3))) unsigned int*)(void*)l, 16, 0, 0);
}

// ---------------- LayerNorm -> bf16 hi/lo split x2[1024][1536] ----------------
__global__ __launch_bounds__(256) void ln_kernel(
    const float* __restrict__ in, const float* __restrict__ w,
    const float* __restrict__ bvec, unsigned short* __restrict__ x2)
{
    int row = blockIdx.x, t = threadIdx.x;
    __shared__ float rs[4], rss[4], stats[2];
    float v[3];
    float s = 0.f, ss = 0.f;
#pragma unroll
    for (int i = 0; i < 3; i++) {
        v[i] = in[row * IN_DIM + i * 256 + t];
        s += v[i]; ss += v[i] * v[i];
    }
    for (int o = 32; o; o >>= 1) { s += __shfl_down(s, o); ss += __shfl_down(ss, o); }
    if ((t & 63) == 0) { rs[t >> 6] = s; rss[t >> 6] = ss; }
    __syncthreads();
    if (t == 0) {
        float S = rs[0] + rs[1] + rs[2] + rs[3];
        float SS = rss[0] + rss[1] + rss[2] + rss[3];
        float mu = S * (1.f / IN_DIM);
        float var = SS * (1.f / IN_DIM) - mu * mu;
        stats[0] = mu; stats[1] = rsqrtf(var + EPS);
    }
    __syncthreads();
    float mu = stats[0], r = stats[1];
#pragma unroll
    for (int i = 0; i < 3; i++) {
        int c = i * 256 + t;
        float val = (v[i] - mu) * r * w[c] + bvec[c];
        unsigned short h = f2bf(val);
        unsigned short lo = f2bf(val - bf2f(h));
        x2[(size_t)row * 1536 + c] = h;
        x2[(size_t)row * 1536 + 768 + c] = lo;
    }
}

// ---------------- fp32 [R,K] -> bf16 split [R,2K] (hi | lo) ----------------
__global__ __launch_bounds__(256) void convert_split(
    const float* __restrict__ in, unsigned short* __restrict__ out, int K)
{
    size_t idx = (size_t)(blockIdx.x * 256 + threadIdx.x) * 8;
    int r = (int)(idx / K);
    int c = (int)(idx - (size_t)r * K);
    float4 a = *(const float4*)(in + idx);
    float4 b = *(const float4*)(in + idx + 4);
    float v[8] = {a.x, a.y, a.z, a.w, b.x, b.y, b.z, b.w};
    u16x8 h, l;
#pragma unroll
    for (int j = 0; j < 8; j++) {
        unsigned short hh = f2bf(v[j]);
        h[j] = hh;
        l[j] = f2bf(v[j] - bf2f(hh));
    }
    size_t ro = (size_t)r * 2 * K;
    *(u16x8*)(out + ro + c)     = h;
    *(u16x8*)(out + ro + K + c) = l;
}

// ---------------- MFMA GEMM: C = epi(A @ W^T [+ bias]) in bf16x3 ----------------
// A2: [M, 2K] bf16 (hi|lo), W2: [N, 2K] bf16 (hi|lo). Conceptual K' = 3K:
//   k0 in [0,K):   A hi * W hi
//   k0 in [K,2K):  A lo * W hi
//   k0 in [2K,3K): A hi * W lo
// EPI 0: raw(+bias); 2: acc+other; 3: other*sigmoid(acc+bias)
// 128x128 tile, 4 waves each 64x64, BK=64, double-buffered LDS,
// XOR-swizzled LDS (k ^= (row&7)<<3, 8-elem granularity) via pre-swizzled global src.
template <int EPI, bool WF32, bool SPLIT>
__global__ __launch_bounds__(256) void gemm_mfma(
    const unsigned short* __restrict__ A2, const unsigned short* __restrict__ W2,
    const float* __restrict__ bias, const float* __restrict__ other,
    float* __restrict__ C, unsigned short* __restrict__ C2,
    int M, int N, int K)
{
    __shared__ short As[2][128 * 64];
    __shared__ short Ws[2][128 * 64];
    const int t = threadIdx.x;
    const int wid = t >> 6, lane = t & 63;
    const int bm = blockIdx.y * 128, bn = blockIdx.x * 128;
    const int wm = wid >> 1, wn = wid & 1;
    const int l15 = lane & 15, l16 = lane >> 4;
    const size_t str = 2 * (size_t)K;
    const int Nm1 = N - 1;
    // staging lane geometry: chunk = c*4+wid covers rows [chunk*8, chunk*8+8)
    const int rsub = lane >> 3;                       // row within chunk
    const int scb  = 8 * ((lane & 7) ^ (lane >> 3));  // pre-swizzled global col block

    f32x4 acc[4][4];
#pragma unroll
    for (int i = 0; i < 4; i++)
#pragma unroll
        for (int j = 0; j < 4; j++) acc[i][j] = (f32x4){0.f, 0.f, 0.f, 0.f};

    const int K3 = 3 * K;
    const int nt = K3 / 64;

    auto stage = [&](int bufidx, int k0) {
        const int Acol = (k0 < 2 * K) ? k0 : k0 - 2 * K;
        const int Wcol = (k0 < K) ? k0 : k0 - K;
        short* Ab = &As[bufidx][0];
        short* Wb = &Ws[bufidx][0];
#pragma unroll
        for (int c = 0; c < 4; c++) {
            int chunk = c * 4 + wid;
            int row = chunk * 8 + rsub;
            int rowW = bn + row; if (rowW > Nm1) rowW = Nm1;   // ragged-N guard
            gload_lds16(A2 + (size_t)(bm + row) * str + Acol + scb, Ab + chunk * 512);
            gload_lds16(W2 + (size_t)rowW * str + Wcol + scb, Wb + chunk * 512);
        }
    };

    stage(0, 0);
    __syncthreads();   // drains vmcnt -> buf0 ready
    int cur = 0;
    for (int it = 0; it < nt; ++it) {
        if (it + 1 < nt) stage(cur ^ 1, (it + 1) * 64);   // DMA overlaps MFMA below
        const short* Ab = &As[cur][0];
        const short* Wb = &Ws[cur][0];
#pragma unroll
        for (int kk = 0; kk < 2; kk++) {
            const int ke = kk * 32 + l16 * 8;
            bf16x8 av[4], bv[4];
#pragma unroll
            for (int mi = 0; mi < 4; mi++) {
                int r = wm * 64 + mi * 16 + l15;
                av[mi] = *(const bf16x8*)(Ab + r * 64 + (ke ^ ((r & 7) << 3)));
            }
#pragma unroll
            for (int ni = 0; ni < 4; ni++) {
                int r = wn * 64 + ni * 16 + l15;
                bv[ni] = *(const bf16x8*)(Wb + r * 64 + (ke ^ ((r & 7) << 3)));
            }
#pragma unroll
            for (int mi = 0; mi < 4; mi++)
#pragma unroll
                for (int ni = 0; ni < 4; ni++)
                    acc[mi][ni] = __builtin_amdgcn_mfma_f32_16x16x32_bf16(
                        av[mi], bv[ni], acc[mi][ni], 0, 0, 0);
        }
        __syncthreads();  // lgkm reads of buf[cur] done + vmcnt drained -> next buf ready
        cur ^= 1;
    }

    // Epilogue. C/D layout: col = lane&15, row = (lane>>4)*4 + reg (m89-verified).
#pragma unroll
    for (int ni = 0; ni < 4; ni++) {
        const int cg = bn + wn * 64 + ni * 16 + l15;
        if (cg >= N) continue;
        const float bz = bias ? bias[cg] : 0.f;
#pragma unroll
        for (int mi = 0; mi < 4; mi++) {
            const int rbase = bm + wm * 64 + mi * 16 + l16 * 4;
#pragma unroll
            for (int rr = 0; rr < 4; rr++) {
                const size_t off = (size_t)(rbase + rr) * N + cg;
                float val = acc[mi][ni][rr] + bz;
                if (EPI == 2) val += other[off];
                else if (EPI == 3) val = other[off] * sigmoidf_(val);
                if (WF32) C[off] = val;
                if (SPLIT) {
                    unsigned short h = f2bf(val);
                    unsigned short lo = f2bf(val - bf2f(h));
                    size_t o2 = (size_t)(rbase + rr) * (2 * (size_t)N) + cg;
                    C2[o2] = h; C2[o2 + N] = lo;
                }
            }
        }
    }
}

// ---------------- gated = (proj + bp) * sigmoid(g1 + bg), + bf16 split ----------------
__global__ __launch_bounds__(256) void gate_mul_kernel(
    const float* __restrict__ gpcat, const float* __restrict__ bg,
    const float* __restrict__ bp, float* __restrict__ gated,
    unsigned short* __restrict__ gated2)
{
    int idx = blockIdx.x * 256 + threadIdx.x;   // B*HID/4
    int b = idx >> 8, j4 = (idx & 255) * 4;
    float4 g = *(const float4*)(gpcat + (size_t)b * 2048 + j4);
    float4 p = *(const float4*)(gpcat + (size_t)b * 2048 + 1024 + j4);
    float4 bgv = *(const float4*)(bg + j4);
    float4 bpv = *(const float4*)(bp + j4);
    float4 r;
    r.x = (p.x + bpv.x) * sigmoidf_(g.x + bgv.x);
    r.y = (p.y + bpv.y) * sigmoidf_(g.y + bgv.y);
    r.z = (p.z + bpv.z) * sigmoidf_(g.z + bgv.z);
    r.w = (p.w + bpv.w) * sigmoidf_(g.w + bgv.w);
    *(float4*)(gated + (size_t)b * 1024 + j4) = r;
    ushort4 h = make_ushort4(f2bf(r.x), f2bf(r.y), f2bf(r.z), f2bf(r.w));
    ushort4 l = make_ushort4(f2bf(r.x - bf2f(h.x)), f2bf(r.y - bf2f(h.y)),
                             f2bf(r.z - bf2f(h.z)), f2bf(r.w - bf2f(h.w)));
    *(ushort4*)(gated2 + (size_t)b * 2048 + j4) = h;
    *(ushort4*)(gated2 + (size_t)b * 2048 + 1024 + j4) = l;
}

// ---------------- Conv shift + depthwise conv + silu ----------------
__global__ __launch_bounds__(256) void conv_kernel(
    const float* __restrict__ conv_state, const float* __restrict__ zxbcdt,
    const float* __restrict__ cw, const float* __restrict__ cb,
    float* __restrict__ newconv, float* __restrict__ xbcp)
{
    int idx = blockIdx.x * 256 + threadIdx.x;     // B*CONV_DIM threads
    int b = idx / CONV_DIM, c = idx - b * CONV_DIM;
    float4 cs = ((const float4*)conv_state)[idx];
    float xin = zxbcdt[(size_t)b * DINP + DIN + c];
    float4 nc = make_float4(cs.y, cs.z, cs.w, xin);
    ((float4*)newconv)[idx] = nc;
    float4 w = ((const float4*)cw)[c];
    float s = nc.x * w.x + nc.y * w.y + nc.z * w.z + nc.w * w.w + cb[c];
    xbcp[idx] = s * sigmoidf_(s);
}

// ---------------- dt / dA ----------------
__global__ __launch_bounds__(256) void dt_kernel(
    const float* __restrict__ zxbcdt, const float* __restrict__ dt_bias,
    const float* __restrict__ A_log, float* __restrict__ dtb, float* __restrict__ dab)
{
    int idx = blockIdx.x * 256 + threadIdx.x;   // B*NH
    int b = idx >> 5, h = idx & 31;
    float raw = zxbcdt[(size_t)b * DINP + DIN + CONV_DIM + h] + dt_bias[h];
    float sp = (raw > 20.f) ? raw : log1pf(expf(raw));
    float A = -expf(A_log[h]);
    dtb[idx] = sp;
    dab[idx] = expf(sp * A);
}

// ---------------- SSM state update + y reduction ----------------
__global__ __launch_bounds__(256) void ssm_kernel(
    const float* __restrict__ ssm_state, const float* __restrict__ xbcp,
    const float* __restrict__ dtb, const float* __restrict__ dab,
    const float* __restrict__ Dp, float* __restrict__ newssm, float* __restrict__ ypre)
{
    int bid = blockIdx.x;           // b*NH + h
    int b = bid >> 5, h = bid & 31, g = h >> 3;
    int t = threadIdx.x;
    __shared__ float xsh[64];
    __shared__ float4 Bsh[16], Csh[16];
    __shared__ float sc[3];
    if (t < 64) xsh[t] = xbcp[(size_t)b * CONV_DIM + h * 64 + t];
    else if (t < 80)  Bsh[t - 64] = ((const float4*)(xbcp + (size_t)b * CONV_DIM + DIN + g * 64))[t - 64];
    else if (t < 96)  Csh[t - 80] = ((const float4*)(xbcp + (size_t)b * CONV_DIM + DIN + NG * DS + g * 64))[t - 80];
    else if (t == 96) sc[0] = dtb[bid];
    else if (t == 97) sc[1] = dab[bid];
    else if (t == 98) sc[2] = Dp[h];
    __syncthreads();
    float sdt = sc[0], sdA = sc[1], sDp = sc[2];
    const float4* sin4 = (const float4*)ssm_state + (size_t)bid * 1024;
    float4* sout4 = (float4*)newssm + (size_t)bid * 1024;
#pragma unroll
    for (int i = 0; i < 4; i++) {
        int idx = i * 256 + t;
        int p = idx >> 4, n4 = idx & 15;
        float4 s = sin4[idx];
        float4 Bv = Bsh[n4], Cv = Csh[n4];
        float coef = sdt * xsh[p];
        float4 ns;
        ns.x = fmaf(s.x, sdA, coef * Bv.x);
        ns.y = fmaf(s.y, sdA, coef * Bv.y);
        ns.z = fmaf(s.z, sdA, coef * Bv.z);
        ns.w = fmaf(s.w, sdA, coef * Bv.w);
        sout4[idx] = ns;
        float part = ns.x * Cv.x + ns.y * Cv.y + ns.z * Cv.z + ns.w * Cv.w;
        for (int o = 8; o; o >>= 1) part += __shfl_down(part, o);
        if ((t & 15) == 0) ypre[(size_t)b * DIN + h * 64 + p] = part + sDp * xsh[p];
    }
}

// ---------------- y * silu(z) + grouped RMS norm -> bf16 split yfin2 ----------------
__global__ __launch_bounds__(128) void gn_kernel(
    const float* __restrict__ ypre, const float* __restrict__ zxbcdt,
    const float* __restrict__ nw, unsigned short* __restrict__ yfin2)
{
    int bg = blockIdx.x;            // b*NG + g
    int b = bg >> 2, g = bg & 3;
    int t = threadIdx.x;
    int col = g * 512 + t * 4;
    float4 yv = *(const float4*)(ypre + (size_t)b * DIN + col);
    float4 zv = *(const float4*)(zxbcdt + (size_t)b * DINP + col);
    float4 y2;
    y2.x = yv.x * zv.x * sigmoidf_(zv.x);
    y2.y = yv.y * zv.y * sigmoidf_(zv.y);
    y2.z = yv.z * zv.z * sigmoidf_(zv.z);
    y2.w = yv.w * zv.w * sigmoidf_(zv.w);
    float ss = y2.x * y2.x + y2.y * y2.y + y2.z * y2.z + y2.w * y2.w;
    for (int o = 32; o; o >>= 1) ss += __shfl_down(ss, o);
    __shared__ float red[2]; __shared__ float rfac;
    if ((t & 63) == 0) red[t >> 6] = ss;
    __syncthreads();
    if (t == 0) rfac = rsqrtf((red[0] + red[1]) * (1.f / 512.f) + EPS);
    __syncthreads();
    float r = rfac;
    float4 w4 = *(const float4*)(nw + col);
    float4 o4 = make_float4(y2.x * r * w4.x, y2.y * r * w4.y, y2.z * r * w4.z, y2.w * r * w4.w);
    ushort4 h = make_ushort4(f2bf(o4.x), f2bf(o4.y), f2bf(o4.z), f2bf(o4.w));
    ushort4 l = make_ushort4(f2bf(o4.x - bf2f(h.x)), f2bf(o4.y - bf2f(h.y)),
                             f2bf(o4.z - bf2f(h.z)), f2bf(o4.w - bf2f(h.w)));
    *(ushort4*)(yfin2 + (size_t)b * 4096 + col) = h;
    *(ushort4*)(yfin2 + (size_t)b * 4096 + 2048 + col) = l;
}

extern "C" void kernel_launch(void* const* d_in, const int* in_sizes, int n_in,
                              void* d_out, int out_size, void* d_ws, size_t ws_size,
                              hipStream_t stream)
{
    const float* frame_feat   = (const float*)d_in[0];
    const float* conv_state   = (const float*)d_in[1];
    const float* ssm_state    = (const float*)d_in[2];
    const float* ln_w         = (const float*)d_in[3];
    const float* ln_b         = (const float*)d_in[4];
    const float* w_in_gate    = (const float*)d_in[5];
    const float* b_in_gate    = (const float*)d_in[6];
    const float* w_input_proj = (const float*)d_in[7];
    const float* b_input_proj = (const float*)d_in[8];
    const float* w_in_proj    = (const float*)d_in[9];
    const float* conv_w       = (const float*)d_in[10];
    const float* conv_b       = (const float*)d_in[11];
    const float* A_log        = (const float*)d_in[12];
    const float* Dp           = (const float*)d_in[13];
    const float* dt_bias      = (const float*)d_in[14];
    const float* norm_w       = (const float*)d_in[15];
    const float* w_out_proj   = (const float*)d_in[16];
    const float* w_out_gate   = (const float*)d_in[17];
    const float* b_out_gate   = (const float*)d_in[18];
    const float* w_proj       = (const float*)d_in[19];
    const float* b_proj       = (const float*)d_in[20];

    float* ws = (float*)d_ws;
    // fp32 temps (ypre aliases gpcat: gpcat dead after gate_mul, ypre written later)
    float* gpcat  = ws + 0;          // 1024*2048 = 2097152
    float* ypre   = gpcat;           // alias
    float* gated  = ws + 2097152;    // 1048576
    float* zxbcdt = ws + 3145728;    // 1024*4640 = 4751360
    float* xbcp   = ws + 7897088;    // 1024*2560 = 2621440
    float* dtb    = ws + 10518528;   // 32768
    float* dab    = ws + 10551296;   // 32768
    float* outpre = ws + 10584064;   // 1048576
    // bf16 (hi|lo) buffers
    unsigned short* u = (unsigned short*)(ws + 11632640);
    unsigned short* x2      = u + 0;          // 1024*1536
    unsigned short* wgp2    = u + 1572864;    // 2048*1536
    unsigned short* gated2  = u + 4718592;    // 1024*2048
    unsigned short* winp2   = u + 6815744;    // 4640*2048
    unsigned short* yfin2   = u + 16318464;   // 1024*4096
    unsigned short* woutp2  = u + 20512768;   // 1024*4096
    unsigned short* outpre2 = u + 24707072;   // 1024*2048
    unsigned short* woutg2  = u + 26804224;   // 1024*2048
    unsigned short* outv2   = u + 28901376;   // 1024*2048
    unsigned short* wproj2  = u + 30998528;   // 512*2048
    // total ws: 11632640*4 + 32047104*2 B ≈ 105.5 MB

    float* out     = (float*)d_out;
    float* clip    = out;                                   // 1024*512
    float* newconv = out + (size_t)B * CLIP;                // 1024*2560*4
    float* newssm  = newconv + (size_t)B * CONV_DIM * 4;    // 1024*32*64*64

    // 1. LayerNorm -> x2 (bf16 hi|lo)
    ln_kernel<<<B, 256, 0, stream>>>(frame_feat, ln_w, ln_b, x2);
    // 2. weight conversions (fp32 -> bf16 hi|lo)
    convert_split<<<384, 256, 0, stream>>>(w_in_gate, wgp2, IN_DIM);
    convert_split<<<384, 256, 0, stream>>>(w_input_proj, wgp2 + (size_t)1024 * 1536, IN_DIM);
    convert_split<<<2320, 256, 0, stream>>>(w_in_proj, winp2, HID);
    convert_split<<<1024, 256, 0, stream>>>(w_out_proj, woutp2, DIN);
    convert_split<<<512, 256, 0, stream>>>(w_out_gate, woutg2, HID);
    convert_split<<<256, 256, 0, stream>>>(w_proj, wproj2, HID);
    // 3. gpcat = x @ [w_in_gate; w_input_proj]^T   (merged, N=2048, K=768)
    gemm_mfma<0, true, false><<<dim3(16, 8), 256, 0, stream>>>(
        x2, wgp2, nullptr, nullptr, gpcat, nullptr, B, 2 * HID, IN_DIM);
    // 4. gated = (proj + bp) * sigmoid(g1 + bg), + split
    gate_mul_kernel<<<1024, 256, 0, stream>>>(gpcat, b_in_gate, b_input_proj, gated, gated2);
    // 5. zxbcdt = gated @ w_in_proj^T   (N=4640 ragged, K=1024)
    gemm_mfma<0, true, false><<<dim3(37, 8), 256, 0, stream>>>(
        gated2, winp2, nullptr, nullptr, zxbcdt, nullptr, B, DINP, HID);
    // 6. conv shift + conv + silu (writes new_conv)
    conv_kernel<<<(B * CONV_DIM) / 256, 256, 0, stream>>>(
        conv_state, zxbcdt, conv_w, conv_b, newconv, xbcp);
    // 7. dt / dA
    dt_kernel<<<(B * NH) / 256, 256, 0, stream>>>(zxbcdt, dt_bias, A_log, dtb, dab);
    // 8. SSM update (writes new_ssm) + y reduction
    ssm_kernel<<<B * NH, 256, 0, stream>>>(ssm_state, xbcp, dtb, dab, Dp, newssm, ypre);
    // 9. y * silu(z) + group RMS norm -> yfin2 (bf16 hi|lo)
    gn_kernel<<<B * NG, 128, 0, stream>>>(ypre, zxbcdt, norm_w, yfin2);
    // 10. outpre = yfin @ w_out_proj^T + gated   (K=2048), + split
    gemm_mfma<2, true, true><<<dim3(8, 8), 256, 0, stream>>>(
        yfin2, woutp2, nullptr, gated, outpre, outpre2, B, HID, DIN);
    // 11. outv = outpre * sigmoid(outpre @ w_out_gate^T + b)  (K=1024), split only
    gemm_mfma<3, false, true><<<dim3(8, 8), 256, 0, stream>>>(
        outpre2, woutg2, b_out_gate, outpre, nullptr, outv2, B, HID, HID);
    // 12. clip = outv @ w_proj^T + b_proj   (N=512, K=1024)
    gemm_mfma<0, true, false><<<dim3(4, 8), 256, 0, stream>>>(
        outv2, wproj2, b_proj, nullptr, clip, nullptr, B, CLIP, HID);
}